// Round 11
// baseline (2690.163 us; speedup 1.0000x reference)
//
#include <hip/hip_runtime.h>

#define T_LEN 16384
#define HDIM 64
#define BATCH 64

// K = DELAY / OS_FACTOR = 1/1.5 = 2/3
#define KBLEND      (2.0f / 3.0f)
#define ONE_MINUS_K (1.0f / 3.0f)
#define KK          (KBLEND * ONE_MINUS_K)

// tanh(x) = 1 - 2/(1 + exp2(C2*x)); C2 = 2*log2(e). Exact algebra.
#define C2    2.8853900817779268f
#define C2K   (C2 * KBLEND)
#define C2KK  (C2 * KK)

typedef _Float16 f16x8 __attribute__((ext_vector_type(8)));
typedef float    f32x4 __attribute__((ext_vector_type(4)));
typedef unsigned int u32x4 __attribute__((ext_vector_type(4)));

__device__ __forceinline__ float lane_bcast(float v, int lane) {
    return __int_as_float(__builtin_amdgcn_readlane(__float_as_int(v), lane));
}

// waves_per_eu(1,1): 512-VGPR budget -> weight frags stay register-resident
// (round 4 evidence: 56->132 VGPRs, 5585->3113 us).
__global__ __launch_bounds__(HDIM)
__attribute__((amdgpu_waves_per_eu(1, 1)))
void rnn_delayline_kernel(
    const float* __restrict__ x,      // [B, T, 1]
    const float* __restrict__ Wih,    // [H, 1]
    const float* __restrict__ Whh,    // [H, H] row-major
    const float* __restrict__ bih,    // [H]
    const float* __restrict__ bhh,    // [H]
    float* __restrict__ out_states,   // [B, T, H]
    float* __restrict__ out_hlast)    // [B, H]
{
    const int lane = threadIdx.x;   // h index, 0..63 (one wave per block)
    const int b    = blockIdx.x;    // batch index

    const float* xb = x + (size_t)b * T_LEN;

    // ---- B fragments: W^T chunks for mfma_f32_16x16x32_f16 (round-10 proven) ----
    f16x8 Bf[8];   // [j*2 + s]
    {
        const int n = lane & 15, g = lane >> 4;
        #pragma unroll
        for (int j = 0; j < 4; ++j) {
            const float* wrow = Whh + (j * 16 + n) * HDIM;
            #pragma unroll
            for (int s = 0; s < 2; ++s) {
                const float4* wp = reinterpret_cast<const float4*>(wrow + s * 32 + g * 8);
                float4 v0 = wp[0], v1 = wp[1];
                Bf[j*2+s] = (f16x8){(_Float16)v0.x, (_Float16)v0.y,
                                    (_Float16)v0.z, (_Float16)v0.w,
                                    (_Float16)v1.x, (_Float16)v1.y,
                                    (_Float16)v1.z, (_Float16)v1.w};
            }
        }
    }

    const float wihC2  = C2 * Wih[lane];
    const float biasC2 = C2 * (bih[lane] + bhh[lane]);

    // bpermute index base: slot j wants pair index pi = (lane>>4)*4 + (j&3) + 16*(j>>2),
    // which lives on source lane 2*pi -> byte index 8*pi.
    const int bpbase = (lane >> 4) << 5;

    // D->dot select: lane l takes D_{l>>4} (all rows of D_j identical; reg 0).
    const bool selLo = ((lane >> 4) & 1) != 0;
    const bool selHi = ((lane >> 4) & 2) != 0;

    // State: dot = W·cell_{t-1}; G = C2*(1-K)*d_{t-2} with d_t = W·h_t.
    float h = 0.0f, dot = 0.0f, G = 0.0f;

    float xcur = xb[lane];          // 64 timesteps of x per chunk, one per lane
    float* outp = out_states + (size_t)b * T_LEN * HDIM + lane;

    const int NCHUNK = T_LEN / HDIM;   // 256
    for (int c = 0; c < NCHUNK; ++c) {
        float xnext = 0.0f;
        if (c + 1 < NCHUNK) xnext = xb[(size_t)(c + 1) * HDIM + lane];

        #pragma unroll 4
        for (int tt = 0; tt < HDIM; ++tt) {
            // In-loop pin: weight frags are loop-carried asm outputs -> resident.
            asm volatile("" : "+v"(Bf[0]), "+v"(Bf[1]), "+v"(Bf[2]), "+v"(Bf[3]),
                              "+v"(Bf[4]), "+v"(Bf[5]), "+v"(Bf[6]), "+v"(Bf[7]));

            // ---- off-chain inputs (ready before dot arrives) ----
            float xt = lane_bcast(xcur, tt);          // x_t (I=1: same for all h)
            float cb = fmaf(xt, wihC2, biasC2) + G;   // C2*xpre_t + G_{t-1}

            // ---- critical chain: fma -> exp2 -> add -> rcp -> fma ----
            float targ = fmaf(C2K, dot, cb);          // C2 * arg_t
            float e    = __builtin_amdgcn_exp2f(targ);
            float r    = __builtin_amdgcn_rcpf(1.0f + e);
            float cell = fmaf(-2.0f, r, 1.0f);        // tanh(arg)

            // ---- pack: f16 RTN + neighbor via DPP (round-7-proven pattern).
            // Even lanes 2i end with pair (c[2i] lo, c[2i+1] hi); odd lanes'
            // order is swapped but bpermute only ever reads even lanes.
            unsigned c16 = (unsigned)__builtin_bit_cast(unsigned short, (_Float16)cell);
            unsigned nb  = (unsigned)__builtin_amdgcn_update_dpp(
                               0, (int)c16, 0xB1, 0xF, 0xF, true); // quad_perm [1,0,3,2]
            int pair = (int)(c16 | (nb << 16));

            // ---- off-chain state updates (overlap the crossbar) ----
            G = fmaf(ONE_MINUS_K, G, C2KK * dot);     // -> G_t
            h = fmaf(KBLEND, cell - h, h);            // h_t = h + K*(cell-h)
            *outp = h;                                // coalesced 256B/wave store
            outp += HDIM;

            // ---- transport: 8x ds_bpermute (crossbar, no LDS memory) ----
            // slot j <- pair from lane 2*((lane>>4)*4 + (j&3) + 16*(j>>2))
            int r0 = __builtin_amdgcn_ds_bpermute(bpbase +   0, pair);
            int r1 = __builtin_amdgcn_ds_bpermute(bpbase +   8, pair);
            int r2 = __builtin_amdgcn_ds_bpermute(bpbase +  16, pair);
            int r3 = __builtin_amdgcn_ds_bpermute(bpbase +  24, pair);
            int r4 = __builtin_amdgcn_ds_bpermute(bpbase + 128, pair);
            int r5 = __builtin_amdgcn_ds_bpermute(bpbase + 136, pair);
            int r6 = __builtin_amdgcn_ds_bpermute(bpbase + 144, pair);
            int r7 = __builtin_amdgcn_ds_bpermute(bpbase + 152, pair);

            f16x8 a0 = __builtin_bit_cast(f16x8, (u32x4){(unsigned)r0, (unsigned)r1,
                                                          (unsigned)r2, (unsigned)r3});
            f16x8 a1 = __builtin_bit_cast(f16x8, (u32x4){(unsigned)r4, (unsigned)r5,
                                                          (unsigned)r6, (unsigned)r7});

            // ---- matvec via 8 MFMA (4 n-tiles x 2 k-tiles, f32 accum) ----
            f32x4 d0 = __builtin_amdgcn_mfma_f32_16x16x32_f16(a0, Bf[0], (f32x4){0,0,0,0}, 0, 0, 0);
            f32x4 d1 = __builtin_amdgcn_mfma_f32_16x16x32_f16(a0, Bf[2], (f32x4){0,0,0,0}, 0, 0, 0);
            f32x4 d2 = __builtin_amdgcn_mfma_f32_16x16x32_f16(a0, Bf[4], (f32x4){0,0,0,0}, 0, 0, 0);
            f32x4 d3 = __builtin_amdgcn_mfma_f32_16x16x32_f16(a0, Bf[6], (f32x4){0,0,0,0}, 0, 0, 0);
            d0 = __builtin_amdgcn_mfma_f32_16x16x32_f16(a1, Bf[1], d0, 0, 0, 0);
            d1 = __builtin_amdgcn_mfma_f32_16x16x32_f16(a1, Bf[3], d1, 0, 0, 0);
            d2 = __builtin_amdgcn_mfma_f32_16x16x32_f16(a1, Bf[5], d2, 0, 0, 0);
            d3 = __builtin_amdgcn_mfma_f32_16x16x32_f16(a1, Bf[7], d3, 0, 0, 0);

            // ---- select dot[lane]: D_{lane>>4}, col lane&15, reg 0 ----
            float t01 = selLo ? d1[0] : d0[0];
            float t23 = selLo ? d3[0] : d2[0];
            dot = selHi ? t23 : t01;                  // dot_t
        }

        xcur = xnext;   // rotate x chunk (register, no LDS)
    }

    out_hlast[b * HDIM + lane] = h;
}

extern "C" void kernel_launch(void* const* d_in, const int* in_sizes, int n_in,
                              void* d_out, int out_size, void* d_ws, size_t ws_size,
                              hipStream_t stream) {
    const float* x   = (const float*)d_in[0];
    const float* Wih = (const float*)d_in[1];
    const float* Whh = (const float*)d_in[2];
    const float* bih = (const float*)d_in[3];
    const float* bhh = (const float*)d_in[4];

    float* out_states = (float*)d_out;
    float* out_hlast  = out_states + (size_t)BATCH * T_LEN * HDIM;

    rnn_delayline_kernel<<<dim3(BATCH), dim3(HDIM), 0, stream>>>(
        x, Wih, Whh, bih, bhh, out_states, out_hlast);
}

// Round 12
// 2331.760 us; speedup vs baseline: 1.1537x; 1.1537x over previous
//
#include <hip/hip_runtime.h>

#define T_LEN 16384
#define HDIM 64
#define BATCH 64
#define RING  128            // 2 chunks of 64 steps (16 KB f16 ring)

// K = DELAY / OS_FACTOR = 1/1.5 = 2/3
#define KBLEND      (2.0f / 3.0f)
#define ONE_MINUS_K (1.0f / 3.0f)
#define KK          (KBLEND * ONE_MINUS_K)

// tanh(x) = 1 - 2/(1 + exp2(C2*x)); C2 = 2*log2(e). Exact algebra.
#define C2    2.8853900817779268f
#define C2K   (C2 * KBLEND)
#define C2KK  (C2 * KK)

typedef _Float16 f16x8 __attribute__((ext_vector_type(8)));
typedef float    f32x4 __attribute__((ext_vector_type(4)));

__device__ __forceinline__ float lane_bcast(float v, int lane) {
    return __int_as_float(__builtin_amdgcn_readlane(__float_as_int(v), lane));
}

// waves_per_eu(1,1): 512-VGPR budget; the 2 waves land on different EUs, so
// the producer keeps a whole SIMD's issue bandwidth to itself.
__global__ __launch_bounds__(2 * HDIM)
__attribute__((amdgpu_waves_per_eu(1, 1)))
void rnn_delayline_kernel(
    const float* __restrict__ x,      // [B, T, 1]
    const float* __restrict__ Wih,    // [H, 1]
    const float* __restrict__ Whh,    // [H, H] row-major
    const float* __restrict__ bih,    // [H]
    const float* __restrict__ bhh,    // [H]
    float* __restrict__ out_states,   // [B, T, H]
    float* __restrict__ out_hlast)    // [B, H]
{
    const int tid  = threadIdx.x;
    const int lane = tid & (HDIM - 1);
    const int b    = blockIdx.x;

    __shared__ __align__(16) _Float16 ring[RING][HDIM];   // cell ring (16 KB)
    __shared__ int flag;                                   // chunks published

    if (tid == 0) flag = 0;
    __syncthreads();        // once, before the sequential work

    const float* xb = x + (size_t)b * T_LEN;
    const int NCHUNK = T_LEN / HDIM;   // 256

    if (tid < HDIM) {
        // ================= wave 0: the serial dependence chain =================
        // B fragments: W^T chunks for mfma_f32_16x16x32_f16 (round-10 proven).
        f16x8 Bf[8];   // [j*2 + s]
        {
            const int n = lane & 15, g = lane >> 4;
            #pragma unroll
            for (int j = 0; j < 4; ++j) {
                const float* wrow = Whh + (j * 16 + n) * HDIM;
                #pragma unroll
                for (int s = 0; s < 2; ++s) {
                    const float4* wp = reinterpret_cast<const float4*>(wrow + s * 32 + g * 8);
                    float4 v0 = wp[0], v1 = wp[1];
                    Bf[j*2+s] = (f16x8){(_Float16)v0.x, (_Float16)v0.y,
                                        (_Float16)v0.z, (_Float16)v0.w,
                                        (_Float16)v1.x, (_Float16)v1.y,
                                        (_Float16)v1.z, (_Float16)v1.w};
                }
            }
        }

        const float wihC2  = C2 * Wih[lane];
        const float biasC2 = C2 * (bih[lane] + bhh[lane]);

        const int  g8    = (lane >> 4) * 8;
        const bool selLo = ((lane >> 4) & 1) != 0;
        const bool selHi = ((lane >> 4) & 2) != 0;

        float dot = 0.0f, G = 0.0f;
        float xcur = xb[lane];

        for (int c = 0; c < NCHUNK; ++c) {
            float xnext = 0.0f;
            if (c + 1 < NCHUNK) xnext = xb[(size_t)(c + 1) * HDIM + lane];
            const int sbase = (c & 1) * 64;

            #pragma unroll 4
            for (int tt = 0; tt < HDIM; ++tt) {
                // Pin: weight frags are loop-carried asm outputs -> resident.
                asm volatile("" : "+v"(Bf[0]), "+v"(Bf[1]), "+v"(Bf[2]), "+v"(Bf[3]),
                                  "+v"(Bf[4]), "+v"(Bf[5]), "+v"(Bf[6]), "+v"(Bf[7]));

                // off-chain inputs
                float xt = lane_bcast(xcur, tt);
                float cb = fmaf(xt, wihC2, biasC2) + G;

                // critical chain: fma -> exp2 -> add -> rcp -> fma
                float targ = fmaf(C2K, dot, cb);
                float e    = __builtin_amdgcn_exp2f(targ);
                float r    = __builtin_amdgcn_rcpf(1.0f + e);
                float cell = fmaf(-2.0f, r, 1.0f);        // tanh(arg)

                const int slot = sbase + tt;
                ring[slot][lane] = (_Float16)cell;        // publish (in-order DS)

                G = fmaf(ONE_MINUS_K, G, C2KK * dot);     // off-chain

                // A frags: 2x ds_read_b128, row-uniform per 16-lane group
                f16x8 a0 = *reinterpret_cast<const f16x8*>(&ring[slot][g8]);
                f16x8 a1 = *reinterpret_cast<const f16x8*>(&ring[slot][32 + g8]);

                // matvec via 8 MFMA (4 n-tiles x 2 k-tiles, f32 accum)
                f32x4 d0 = __builtin_amdgcn_mfma_f32_16x16x32_f16(a0, Bf[0], (f32x4){0,0,0,0}, 0, 0, 0);
                f32x4 d1 = __builtin_amdgcn_mfma_f32_16x16x32_f16(a0, Bf[2], (f32x4){0,0,0,0}, 0, 0, 0);
                f32x4 d2 = __builtin_amdgcn_mfma_f32_16x16x32_f16(a0, Bf[4], (f32x4){0,0,0,0}, 0, 0, 0);
                f32x4 d3 = __builtin_amdgcn_mfma_f32_16x16x32_f16(a0, Bf[6], (f32x4){0,0,0,0}, 0, 0, 0);
                d0 = __builtin_amdgcn_mfma_f32_16x16x32_f16(a1, Bf[1], d0, 0, 0, 0);
                d1 = __builtin_amdgcn_mfma_f32_16x16x32_f16(a1, Bf[3], d1, 0, 0, 0);
                d2 = __builtin_amdgcn_mfma_f32_16x16x32_f16(a1, Bf[5], d2, 0, 0, 0);
                d3 = __builtin_amdgcn_mfma_f32_16x16x32_f16(a1, Bf[7], d3, 0, 0, 0);

                // select dot[lane]: D_{lane>>4}, col lane&15, reg 0
                float t01 = selLo ? d1[0] : d0[0];
                float t23 = selLo ? d3[0] : d2[0];
                dot = selHi ? t23 : t01;
            }

            xcur = xnext;
            // publish chunk c (release: drains this wave's DS queue first)
            if (lane == 0)
                __hip_atomic_store(&flag, c + 1, __ATOMIC_RELEASE,
                                   __HIP_MEMORY_SCOPE_WORKGROUP);
        }
    } else {
        // ================= wave 1: h recurrence + all global stores =================
        float h = 0.0f;
        float* outp = out_states + (size_t)b * T_LEN * HDIM + lane;

        for (int c = 0; c < NCHUNK; ++c) {
            // acquire-poll; s_sleep keeps the DS pipe clear for wave 0
            while (__hip_atomic_load(&flag, __ATOMIC_ACQUIRE,
                                     __HIP_MEMORY_SCOPE_WORKGROUP) <= c) {
                __builtin_amdgcn_s_sleep(2);
            }
            const int sbase = (c & 1) * 64;
            #pragma unroll 4
            for (int tt = 0; tt < HDIM; ++tt) {
                float cell = (float)ring[sbase + tt][lane];
                h = fmaf(KBLEND, cell - h, h);      // h_t = h + K*(cell-h)
                *outp = h;                          // coalesced 256B/wave store
                outp += HDIM;
            }
        }
        out_hlast[b * HDIM + lane] = h;
    }
}

extern "C" void kernel_launch(void* const* d_in, const int* in_sizes, int n_in,
                              void* d_out, int out_size, void* d_ws, size_t ws_size,
                              hipStream_t stream) {
    const float* x   = (const float*)d_in[0];
    const float* Wih = (const float*)d_in[1];
    const float* Whh = (const float*)d_in[2];
    const float* bih = (const float*)d_in[3];
    const float* bhh = (const float*)d_in[4];

    float* out_states = (float*)d_out;
    float* out_hlast  = out_states + (size_t)BATCH * T_LEN * HDIM;

    rnn_delayline_kernel<<<dim3(BATCH), dim3(2 * HDIM), 0, stream>>>(
        x, Wih, Whh, bih, bhh, out_states, out_hlast);
}